// Round 18
// baseline (542.425 us; speedup 1.0000x reference)
//
#include <hip/hip_runtime.h>
#include <hip/hip_bf16.h>

// MultiHeadAttention fused pipeline for MI355X (gfx950).
// Outputs: [0] out (2*2048*1024 f32), [1] attn (2*16*2048*2048 f32), concatenated in d_out.
// ws layout: [flag:256B][qh 8MB][kh 8MB][vt 8MB][ao 8MB][wt 8MB][mbits 1MB][qc 8][kc 8][vc 8] = ~66MB.

typedef __attribute__((ext_vector_type(8))) short bf16x8;
typedef __attribute__((ext_vector_type(8))) _Float16 f16x8;
typedef __attribute__((ext_vector_type(4))) float f32x4;
typedef __attribute__((ext_vector_type(4))) int i32x4;
typedef __attribute__((ext_vector_type(4))) _Float16 f16x4;
typedef unsigned short u16;

#define NB 2
#define QL 2048
#define KL 2048
#define CH 1024
#define NH 16
#define HD 64
#define SH_STRIDE 2600    // 16-row fallback attn stride
#define S32_STRIDE 2344   // 32-row attn stride: row 4688B (16B-aligned), 1172dw%32=20 (spread banks)

__device__ __forceinline__ u16 f2bf(float f){
  unsigned u = __float_as_uint(f);
  u += 0x7fffu + ((u >> 16) & 1u);   // RNE
  return (u16)(u >> 16);
}
__device__ __forceinline__ u16 f2h(float f){
  _Float16 h = (_Float16)f;
  return *(u16*)&h;
}

// ---------------- mask dtype detector: int32 0/1 vs packed bool bytes ----------------
__global__ void k_detect(const unsigned int* __restrict__ m, int* __restrict__ flag){
  unsigned v = m[threadIdx.x];
  unsigned long long b = __ballot(v > 1u);
  __shared__ int r[4];
  if ((threadIdx.x & 63) == 0) r[threadIdx.x >> 6] = (b != 0ULL);
  __syncthreads();
  if (threadIdx.x == 0) *flag = (r[0] | r[1] | r[2] | r[3]);
}

// ---------------- mask -> 1 bit/elem (1MB; L2/L3-resident) ----------------
__global__ __launch_bounds__(256) void k_maskpack(const void* __restrict__ maskp, const int* __restrict__ flag,
                                                  unsigned* __restrict__ mbits){
  const int idx = blockIdx.x*256 + threadIdx.x;
  unsigned out = 0;
  if (*flag){
    const unsigned* m8 = (const unsigned*)maskp + (size_t)idx*8;
    #pragma unroll
    for (int j=0;j<8;++j){
      unsigned wv = m8[j];
      out |= ((wv & 1u) | ((wv>>7)&2u) | ((wv>>14)&4u) | ((wv>>21)&8u)) << (4*j);
    }
  } else {
    const i32x4* m32 = (const i32x4*)maskp + (size_t)idx*8;
    #pragma unroll
    for (int j=0;j<8;++j){
      i32x4 v = m32[j];
      out |= (unsigned)((v[0]&1) | ((v[1]&1)<<1) | ((v[2]&1)<<2) | ((v[3]&1)<<3)) << (4*j);
    }
  }
  mbits[idx] = out;
}

// ---------------- merged prep: weight transpose (blocks 0..4095) + qkv f32->bf16 cvt (4096..10239) ----------------
__global__ __launch_bounds__(256) void k_prep(const float* __restrict__ Wq, const float* __restrict__ Wk,
                                              const float* __restrict__ Wv, const float* __restrict__ Wo,
                                              u16* __restrict__ wt,
                                              const float* __restrict__ q, const float* __restrict__ k,
                                              const float* __restrict__ v,
                                              u16* __restrict__ qc, u16* __restrict__ kc, u16* __restrict__ vc){
  const int bx = blockIdx.x;
  if (bx < 4096){
    // transpose: z = bx>>10, tile = bx&1023 -> (x,y)
    const int z = bx >> 10, rem = bx & 1023;
    const int xt = rem & 31, yt = rem >> 5;
    const float* src = z==0 ? Wq : z==1 ? Wk : z==2 ? Wv : Wo;
    u16* dst = wt + (size_t)z * CH * CH;
    __shared__ float t[32][33];
    const int x = xt*32, y = yt*32;
    const int tx = threadIdx.x & 31, ty = threadIdx.x >> 5;
    #pragma unroll
    for (int j=0;j<32;j+=8) t[ty+j][tx] = src[(size_t)(y+ty+j)*CH + x + tx];
    __syncthreads();
    #pragma unroll
    for (int j=0;j<32;j+=8) dst[(size_t)(x+ty+j)*CH + y + tx] = f2bf(t[tx][ty+j]);
  } else {
    const int idx = bx - 4096;                  // 0..6143
    const int s = idx / 2048, blk = idx % 2048; // s: 0=q 1=k 2=v
    const float* in = s==0 ? q : s==1 ? k : v;
    u16* out = s==0 ? qc : s==1 ? kc : vc;
    const size_t i = ((size_t)blk*256 + threadIdx.x)*8;
    float4 lo = *(const float4*)&in[i];
    float4 hi = *(const float4*)&in[i+4];
    ushort4 a, b;
    a.x=f2bf(lo.x); a.y=f2bf(lo.y); a.z=f2bf(lo.z); a.w=f2bf(lo.w);
    b.x=f2bf(hi.x); b.y=f2bf(hi.y); b.z=f2bf(hi.z); b.w=f2bf(hi.w);
    *(ushort4*)&out[i] = a;
    *(ushort4*)&out[i+4] = b;
  }
}

// ---------------- 128x128 tile, 8-wave, BK=64, global_load_lds GEMM core (m97 structure) ----------------
__device__ __forceinline__ void gemm128_core(const u16* __restrict__ A, const u16* __restrict__ Bt,
                                             int m0, int n0, f32x4 acc[2][4]){
  __shared__ u16 As[128*64];
  __shared__ u16 Bs[128*64];
  const int tid = threadIdx.x, lane = tid & 63, w = tid >> 6;
  const int wm = w >> 1, wn = w & 1;
  const int lr = lane & 15, lg = lane >> 4;
  for (int k0 = 0; k0 < CH; k0 += 64){
    #pragma unroll
    for (int r=0;r<2;++r){
      const int chunk = r*512 + tid;
      const int row = chunk >> 3, ch = chunk & 7;
      __builtin_amdgcn_global_load_lds(
        (const __attribute__((address_space(1))) void*)&A[(size_t)(m0+row)*CH + k0 + ch*8],
        (__attribute__((address_space(3))) void*)&As[(r*512 + w*64)*8], 16, 0, 0);
      __builtin_amdgcn_global_load_lds(
        (const __attribute__((address_space(1))) void*)&Bt[(size_t)(n0+row)*CH + k0 + ch*8],
        (__attribute__((address_space(3))) void*)&Bs[(r*512 + w*64)*8], 16, 0, 0);
    }
    __syncthreads();
    #pragma unroll
    for (int kk=0; kk<2; ++kk){
      bf16x8 a0 = *(const bf16x8*)&As[(wm*32      + lr)*64 + (kk*4+lg)*8];
      bf16x8 a1 = *(const bf16x8*)&As[(wm*32 + 16 + lr)*64 + (kk*4+lg)*8];
      #pragma unroll
      for (int fj=0;fj<4;++fj){
        bf16x8 b = *(const bf16x8*)&Bs[(wn*64 + fj*16 + lr)*64 + (kk*4+lg)*8];
        acc[0][fj] = __builtin_amdgcn_mfma_f32_16x16x32_bf16(a0, b, acc[0][fj], 0,0,0);
        acc[1][fj] = __builtin_amdgcn_mfma_f32_16x16x32_bf16(a1, b, acc[1][fj], 0,0,0);
      }
    }
    __syncthreads();
  }
}

__global__ __launch_bounds__(512) void k_gemm_qkv3(const u16* __restrict__ qc, const u16* __restrict__ kc,
                                                   const u16* __restrict__ vc, const u16* __restrict__ wt,
                                                   const float* __restrict__ bq, const float* __restrict__ bk,
                                                   const float* __restrict__ bv,
                                                   u16* __restrict__ qh, u16* __restrict__ kh, u16* __restrict__ vt){
  const int z = blockIdx.x >> 3;
  const int n0 = (blockIdx.x & 7) * 128;
  const int m0 = blockIdx.y * 128;
  const u16* A  = z==0 ? qc : z==1 ? kc : vc;
  const u16* Bt = wt + (size_t)z*CH*CH;
  const float* bias = z==0 ? bq : z==1 ? bk : bv;
  const float scale = z==0 ? 0.03125f : 1.0f;
  u16* qk_dst = z==0 ? qh : kh;
  f32x4 acc[2][4] = {};
  gemm128_core(A, Bt, m0, n0, acc);
  const int lane = threadIdx.x & 63, w = threadIdx.x >> 6;
  const int wm = w >> 1, wn = w & 1;
  const int lr = lane & 15, lg = lane >> 4;
  #pragma unroll
  for (int fi=0;fi<2;++fi)
  #pragma unroll
  for (int fj=0;fj<4;++fj)
  #pragma unroll
  for (int r=0;r<4;++r){
    int row = m0 + wm*32 + fi*16 + lg*4 + r;
    int col = n0 + wn*64 + fj*16 + lr;
    float val = (acc[fi][fj][r] + bias[col]) * scale;
    int bb = row >> 11, ll = row & 2047, hh = col >> 6, dd = col & 63;
    if (z < 2) qk_dst[(((size_t)(bb*NH+hh)*QL + ll) << 6) + dd] = f2bf(val);
    else       vt[(((size_t)(bb*NH+hh) << 6) + dd)*KL + ll] = f2h(val);
  }
}

__global__ __launch_bounds__(512) void k_gemm_out3(const u16* __restrict__ ao, const u16* __restrict__ wto,
                                                   const float* __restrict__ bo, float* __restrict__ out){
  const int n0 = blockIdx.x * 128, m0 = blockIdx.y * 128;
  f32x4 acc[2][4] = {};
  gemm128_core(ao, wto, m0, n0, acc);
  const int lane = threadIdx.x & 63, w = threadIdx.x >> 6;
  const int wm = w >> 1, wn = w & 1;
  const int lr = lane & 15, lg = lane >> 4;
  #pragma unroll
  for (int fi=0;fi<2;++fi)
  #pragma unroll
  for (int fj=0;fj<4;++fj)
  #pragma unroll
  for (int r=0;r<4;++r){
    int row = m0 + wm*32 + fi*16 + lg*4 + r;
    int col = n0 + wn*64 + fj*16 + lr;
    out[(size_t)row*CH + col] = acc[fi][fj][r] + bo[col];
  }
}

// ---------------- legacy f32-input projection GEMMs (fallback when ws too small) ----------------
__global__ __launch_bounds__(256) void k_gemm_qkv(const float* __restrict__ q, const float* __restrict__ k,
                                                  const float* __restrict__ v, const u16* __restrict__ wt,
                                                  const float* __restrict__ bq, const float* __restrict__ bk,
                                                  const float* __restrict__ bv,
                                                  u16* __restrict__ qh, u16* __restrict__ kh, u16* __restrict__ vt){
  const int z = blockIdx.z;
  const float* A = z==0 ? q : z==1 ? k : v;
  const u16* Bt = wt + (size_t)z*CH*CH;
  const float* bias = z==0 ? bq : z==1 ? bk : bv;
  u16* Cp = z==0 ? qh : z==1 ? kh : vt;
  const float scale = (z==0) ? 0.03125f : 1.0f;
  __shared__ u16 As[64][72];
  __shared__ u16 Bs[64][72];
  const int m0 = blockIdx.y*64, n0 = blockIdx.x*64;
  const int tid = threadIdx.x, lane = tid & 63, w = tid >> 6;
  const int wm = w >> 1, wn = w & 1;
  const int lr = lane & 15, lg = lane >> 4;
  f32x4 acc[2][2] = {};
  for (int k0 = 0; k0 < CH; k0 += 64){
    #pragma unroll
    for (int j=0;j<4;++j){
      int idx = tid + 256*j, r = idx >> 4, c = (idx & 15)*4;
      float4 vv = *(const float4*)&A[(size_t)(m0+r)*CH + k0 + c];
      ushort4 s; s.x=f2bf(vv.x); s.y=f2bf(vv.y); s.z=f2bf(vv.z); s.w=f2bf(vv.w);
      *(ushort4*)&As[r][c] = s;
    }
    #pragma unroll
    for (int j=0;j<2;++j){
      int idx = tid + 256*j, r = idx >> 3, c = (idx & 7)*8;
      *(uint4*)&Bs[r][c] = *(const uint4*)&Bt[(size_t)(n0+r)*CH + k0 + c];
    }
    __syncthreads();
    #pragma unroll
    for (int kk=0; kk<2; ++kk){
      bf16x8 a0 = *(const bf16x8*)&As[wm*32      + lr][kk*32 + lg*8];
      bf16x8 a1 = *(const bf16x8*)&As[wm*32 + 16 + lr][kk*32 + lg*8];
      bf16x8 b0 = *(const bf16x8*)&Bs[wn*32      + lr][kk*32 + lg*8];
      bf16x8 b1 = *(const bf16x8*)&Bs[wn*32 + 16 + lr][kk*32 + lg*8];
      acc[0][0] = __builtin_amdgcn_mfma_f32_16x16x32_bf16(a0,b0,acc[0][0],0,0,0);
      acc[0][1] = __builtin_amdgcn_mfma_f32_16x16x32_bf16(a0,b1,acc[0][1],0,0,0);
      acc[1][0] = __builtin_amdgcn_mfma_f32_16x16x32_bf16(a1,b0,acc[1][0],0,0,0);
      acc[1][1] = __builtin_amdgcn_mfma_f32_16x16x32_bf16(a1,b1,acc[1][1],0,0,0);
    }
    __syncthreads();
  }
  #pragma unroll
  for (int fi=0;fi<2;++fi)
  #pragma unroll
  for (int fj=0;fj<2;++fj)
  #pragma unroll
  for (int r=0;r<4;++r){
    int row = m0 + wm*32 + fi*16 + lg*4 + r;
    int col = n0 + wn*32 + fj*16 + lr;
    float val = (acc[fi][fj][r] + bias[col]) * scale;
    int bb = row >> 11, ll = row & 2047, hh = col >> 6, dd = col & 63;
    if (z < 2) Cp[(((size_t)(bb*NH+hh)*QL + ll) << 6) + dd] = f2bf(val);
    else       Cp[(((size_t)(bb*NH+hh) << 6) + dd)*KL + ll] = f2h(val);
  }
}

__global__ __launch_bounds__(256) void k_gemm_out(const u16* __restrict__ Ap, const u16* __restrict__ Bt,
                                                  const float* __restrict__ bias, float* __restrict__ Cp){
  __shared__ u16 As[64][72];
  __shared__ u16 Bs[64][72];
  const int m0 = blockIdx.y*64, n0 = blockIdx.x*64;
  const int tid = threadIdx.x, lane = tid & 63, w = tid >> 6;
  const int wm = w >> 1, wn = w & 1;
  const int lr = lane & 15, lg = lane >> 4;
  f32x4 acc[2][2] = {};
  for (int k0 = 0; k0 < CH; k0 += 64){
    #pragma unroll
    for (int j=0;j<2;++j){
      int idx = tid + 256*j, r = idx >> 3, c = (idx & 7)*8;
      *(uint4*)&As[r][c] = *(const uint4*)&Ap[(size_t)(m0+r)*CH + k0 + c];
      *(uint4*)&Bs[r][c] = *(const uint4*)&Bt[(size_t)(n0+r)*CH + k0 + c];
    }
    __syncthreads();
    #pragma unroll
    for (int kk=0; kk<2; ++kk){
      bf16x8 a0 = *(const bf16x8*)&As[wm*32      + lr][kk*32 + lg*8];
      bf16x8 a1 = *(const bf16x8*)&As[wm*32 + 16 + lr][kk*32 + lg*8];
      bf16x8 b0 = *(const bf16x8*)&Bs[wn*32      + lr][kk*32 + lg*8];
      bf16x8 b1 = *(const bf16x8*)&Bs[wn*32 + 16 + lr][kk*32 + lg*8];
      acc[0][0] = __builtin_amdgcn_mfma_f32_16x16x32_bf16(a0,b0,acc[0][0],0,0,0);
      acc[0][1] = __builtin_amdgcn_mfma_f32_16x16x32_bf16(a0,b1,acc[0][1],0,0,0);
      acc[1][0] = __builtin_amdgcn_mfma_f32_16x16x32_bf16(a1,b0,acc[1][0],0,0,0);
      acc[1][1] = __builtin_amdgcn_mfma_f32_16x16x32_bf16(a1,b1,acc[1][1],0,0,0);
    }
    __syncthreads();
  }
  #pragma unroll
  for (int fi=0;fi<2;++fi)
  #pragma unroll
  for (int fj=0;fj<2;++fj)
  #pragma unroll
  for (int r=0;r<4;++r){
    int row = m0 + wm*32 + fi*16 + lg*4 + r;
    int col = n0 + wn*32 + fj*16 + lr;
    Cp[(size_t)row*CH + col] = acc[fi][fj][r] + bias[col];
  }
}

// ---------------- 32-row fused attention (8 serial blocks/CU; g1-bias prefetch) ----------------
__global__ __launch_bounds__(1024, 1) void k_attn32(const u16* __restrict__ qh, const u16* __restrict__ kh,
                                              const _Float16* __restrict__ vt, const float* __restrict__ bias,
                                              const unsigned* __restrict__ mbits,
                                              float* __restrict__ attn, u16* __restrict__ ao){
  __shared__ _Float16 Sh[32][S32_STRIDE];   // 150.0 KB
  __shared__ float wsum[16][32];            // 2 KB
  __shared__ float inv_l[32];
  const int qt = blockIdx.x, h = blockIdx.y, b = blockIdx.z;
  const int q0 = qt*32, bh = b*NH + h;
  const int tid = threadIdx.x, lane = tid & 63, w = tid >> 6;
  const int lr = lane & 15, lg = lane >> 4;
  const float* bb = bias + ((size_t)bh*QL + q0)*KL;
  const u16* khb = kh + (size_t)bh*KL*HD;
  const _Float16* vtb = vt + (size_t)bh*HD*KL;
  const int c0 = w*128;

  // ---- phase 1: hoist BOTH groups' bias loads (g1 in flight during g0 compute) ----
  f32x4 bi0[8], bi1[8];
  unsigned mwd[8];
  #pragma unroll
  for (int ct=0; ct<8; ++ct){
    const int cb = c0 + ct*16 + lg*4;
    bi0[ct] = *(const f32x4*)&bb[(size_t)lr*KL + cb];
    mwd[ct] = mbits[((size_t)b*QL + q0 + lr)*(KL/32) + (cb>>5)];
  }
  #pragma unroll
  for (int ct=0; ct<8; ++ct){
    const int cb = c0 + ct*16 + lg*4;
    bi1[ct] = *(const f32x4*)&bb[(size_t)(16+lr)*KL + cb];
  }
  #pragma unroll
  for (int g=0; g<2; ++g){
    const int qrow = q0 + g*16;
    const u16* qb = qh + ((size_t)bh*QL + qrow)*HD;
    const bf16x8 qf0 = *(const bf16x8*)&qb[lr*HD +      lg*8];
    const bf16x8 qf1 = *(const bf16x8*)&qb[lr*HD + 32 + lg*8];
    if (g == 1){
      #pragma unroll
      for (int ct=0; ct<8; ++ct){
        const int cb = c0 + ct*16 + lg*4;
        mwd[ct] = mbits[((size_t)b*QL + qrow + lr)*(KL/32) + (cb>>5)];   // L2-resident, cheap
      }
    }
    float ps = 0.f;
    #pragma unroll
    for (int ct=0; ct<8; ++ct){
      const int cb = c0 + ct*16 + lg*4;
      f32x4 acc = g==0 ? bi0[ct] : bi1[ct];
      const int kcol = c0 + ct*16 + lr;
      bf16x8 kf0 = *(const bf16x8*)&khb[(size_t)kcol*HD +      lg*8];
      bf16x8 kf1 = *(const bf16x8*)&khb[(size_t)kcol*HD + 32 + lg*8];
      acc = __builtin_amdgcn_mfma_f32_16x16x32_bf16(kf0, qf0, acc, 0,0,0);   // swapped: D = S^T frag
      acc = __builtin_amdgcn_mfma_f32_16x16x32_bf16(kf1, qf1, acc, 0,0,0);
      const unsigned msel = (mwd[ct] >> (cb & 31)) & 0xFu;
      f16x4 sv;
      #pragma unroll
      for (int r=0;r<4;++r){
        float e = ((msel >> r) & 1u) ? 0.f : __expf(acc[r]);   // bounded logits: no max-sub
        sv[r] = (_Float16)e;
        ps += e;
      }
      *(f16x4*)&Sh[g*16+lr][cb] = sv;
    }
    ps += __shfl_xor(ps, 16);
    ps += __shfl_xor(ps, 32);
    if (lane < 16) wsum[w][g*16+lr] = ps;
  }
  __syncthreads();
  if (tid < 32){
    float s = 0.f;
    #pragma unroll
    for (int ww=0; ww<16; ++ww) s += wsum[ww][tid];
    inv_l[tid] = 1.f / s;
  }
  __syncthreads();

  if (w < 8){
    // ---- PV: d-strip (w&3)*16, row-half (w>>2)*16, full K; direct ao write ----
    const int d0 = (w & 3)*16, rh = (w >> 2)*16;
    f32x4 oacc = {};
    #pragma unroll
    for (int kb=0; kb<8; ++kb){
      f16x8 vf[8], af[8];
      #pragma unroll
      for (int i=0;i<8;++i){
        vf[i] = *(const f16x8*)&vtb[(size_t)(d0+lr)*KL + kb*256 + i*32 + lg*8];
        af[i] = *(const f16x8*)&Sh[rh+lr][kb*256 + i*32 + lg*8];
      }
      #pragma unroll
      for (int i=0;i<8;++i)
        oacc = __builtin_amdgcn_mfma_f32_16x16x32_f16(af[i], vf[i], oacc, 0,0,0);
    }
    #pragma unroll
    for (int r=0;r<4;++r){
      const int row = rh + lg*4 + r;
      ao[((size_t)b*QL + q0 + row)*CH + h*HD + d0 + lr] = f2bf(oacc[r] * inv_l[row]);
    }
  } else {
    // ---- writers: 4 rows each, normalized f32 attn, 1KB contiguous per instruction ----
    float* ob = attn + ((size_t)bh*QL + q0)*KL;
    const int r0 = (w - 8)*4;
    #pragma unroll
    for (int rr=0; rr<4; ++rr){
      const int row = r0 + rr;
      const float ivr = inv_l[row];
      float* orow = ob + (size_t)row*KL;
      #pragma unroll
      for (int ch=0; ch<8; ++ch){
        f16x4 hv = *(const f16x4*)&Sh[row][ch*256 + lane*4];
        f32x4 v;
        v[0]=(float)hv[0]*ivr; v[1]=(float)hv[1]*ivr; v[2]=(float)hv[2]*ivr; v[3]=(float)hv[3]*ivr;
        *(f32x4*)&orow[ch*256 + lane*4] = v;
      }
    }
  }
}

// ---------------- 16-row fused attention fallback (no mbits workspace) ----------------
template<int BITS>
__global__ __launch_bounds__(1024, 1) void k_attn(const u16* __restrict__ qh, const u16* __restrict__ kh,
                                              const _Float16* __restrict__ vt, const float* __restrict__ bias,
                                              const void* __restrict__ maskp, const int* __restrict__ flag,
                                              const unsigned* __restrict__ mbits,
                                              float* __restrict__ attn, u16* __restrict__ ao){
  __shared__ _Float16 Sh[16][SH_STRIDE];
  __shared__ float osum[8][16][17];
  __shared__ float wsum[16][16];
  __shared__ float inv_l[16];
  const int qt = BITS ? blockIdx.x : blockIdx.y;
  const int h  = BITS ? blockIdx.y : blockIdx.x;
  const int b  = blockIdx.z;
  const int q0 = qt*16, bh = b*NH + h;
  const int tid = threadIdx.x, lane = tid & 63, w = tid >> 6;
  const int lr = lane & 15, lg = lane >> 4;
  const u16* qb = qh + ((size_t)bh*QL + q0)*HD;
  const bf16x8 qf0 = *(const bf16x8*)&qb[lr*HD +      lg*8];
  const bf16x8 qf1 = *(const bf16x8*)&qb[lr*HD + 32 + lg*8];
  const float* bb = bias + ((size_t)bh*QL + q0)*KL;
  const u16* khb = kh + (size_t)bh*KL*HD;
  const _Float16* vtb = vt + (size_t)bh*HD*KL;
  const int c0 = w*128;

  f32x4 bi[8];
  unsigned mwd[8];
  #pragma unroll
  for (int ct=0; ct<8; ++ct){
    const int cb = c0 + ct*16 + lg*4;
    bi[ct] = *(const f32x4*)&bb[(size_t)lr*KL + cb];
    if (BITS) mwd[ct] = mbits[((size_t)b*QL + q0 + lr)*(KL/32) + (cb>>5)];
  }
  const int isbool = BITS ? 0 : *flag;
  const unsigned char* mb8 = (const unsigned char*)maskp + ((size_t)b*QL + q0)*KL;
  const int* mb32 = (const int*)maskp + ((size_t)b*QL + q0)*KL;

  float ps = 0.f;
  #pragma unroll
  for (int ct=0; ct<8; ++ct){
    const int cb = c0 + ct*16 + lg*4;
    f32x4 acc = bi[ct];
    const int kcol = c0 + ct*16 + lr;
    bf16x8 kf0 = *(const bf16x8*)&khb[(size_t)kcol*HD +      lg*8];
    bf16x8 kf1 = *(const bf16x8*)&khb[(size_t)kcol*HD + 32 + lg*8];
    acc = __builtin_amdgcn_mfma_f32_16x16x32_bf16(kf0, qf0, acc, 0,0,0);
    acc = __builtin_amdgcn_mfma_f32_16x16x32_bf16(kf1, qf1, acc, 0,0,0);
    unsigned msel;
    i32x4 mv;
    if (BITS){
      msel = (mwd[ct] >> (cb & 31)) & 0xFu;
    } else if (isbool){
      unsigned mw = *(const unsigned*)&mb8[(size_t)lr*KL + cb];
      msel = (mw&1u) | ((mw>>7)&2u) | ((mw>>14)&4u) | ((mw>>21)&8u);
    } else {
      mv = *(const i32x4*)&mb32[(size_t)lr*KL + cb];
      msel = (unsigned)((mv[0]&1) | ((mv[1]&1)<<1) | ((mv[2]&1)<<2) | ((mv[3]&1)<<3));
    }
    f16x4 sv;
    #pragma unroll
    for (int r=0;r<4;++r){
      float e = ((msel >> r) & 1u) ? 0.f : __expf(acc[r]);
      sv[r] = (_Float16)e;
      ps += e;
    }
    *(f16x4*)&Sh[lr][cb] = sv;
  }
  ps += __shfl_xor(ps, 16);
  ps += __shfl_xor(ps, 32);
  if (lane < 16) wsum[w][lr] = ps;
  __syncthreads();
  if (tid < 16){
    float s = 0.f;
    #pragma unroll
    for (int ww=0; ww<16; ++ww) s += wsum[ww][tid];
    inv_l[tid] = 1.f / s;
  }
  __syncthreads();

  if (w < 8){
    const int d0 = (w & 3)*16, kb0 = (w >> 2)*1024;
    f32x4 oacc = {};
    #pragma unroll
    for (int kb=0; kb<4; ++kb){
      f16x8 vf[8];
      #pragma unroll
      for (int i=0;i<8;++i)
        vf[i] = *(const f16x8*)&vtb[(size_t)(d0+lr)*KL + kb0 + kb*256 + i*32 + lg*8];
      #pragma unroll
      for (int i=0;i<8;++i){
        f16x8 a = *(const f16x8*)&Sh[lr][kb0 + kb*256 + i*32 + lg*8];
        oacc = __builtin_amdgcn_mfma_f32_16x16x32_f16(a, vf[i], oacc, 0,0,0);
      }
    }
    #pragma unroll
    for (int r=0;r<4;++r) osum[w][lg*4+r][lr] = oacc[r];
  } else {
    float* ob = attn + ((size_t)bh*QL + q0)*KL;
    const int r0 = (w - 8)*2;
    #pragma unroll
    for (int rr=0; rr<2; ++rr){
      const int row = r0 + rr;
      const float ivr = inv_l[row];
      #pragma unroll
      for (int ch=0; ch<8; ++ch){
        f16x4 hv = *(const f16x4*)&Sh[row][ch*256 + lane*4];
        f32x4 v;
        v[0]=(float)hv[0]*ivr; v[1]=(float)hv[1]*ivr; v[2]=(float)hv[2]*ivr; v[3]=(float)hv[3]*ivr;
        *(f32x4*)&ob[(size_t)row*KL + ch*256 + lane*4] = v;
      }
    }
  }
  __syncthreads();
  {
    const int row = tid >> 6, d = tid & 63;
    float o = (osum[d >> 4][row][d & 15] + osum[4 + (d >> 4)][row][d & 15]) * inv_l[row];
    ao[((size_t)b*QL + q0 + row)*CH + h*HD + d] = f2bf(o);
  }
}

extern "C" void kernel_launch(void* const* d_in, const int* in_sizes, int n_in,
                              void* d_out, int out_size, void* d_ws, size_t ws_size,
                              hipStream_t stream){
  const float* q    = (const float*)d_in[0];
  const float* k    = (const float*)d_in[1];
  const float* v    = (const float*)d_in[2];
  const void*  mask = d_in[3];
  const float* bias = (const float*)d_in[4];
  const float* Wq   = (const float*)d_in[5];
  const float* bq   = (const float*)d_in[6];
  const float* Wk   = (const float*)d_in[7];
  const float* bk   = (const float*)d_in[8];
  const float* Wv   = (const float*)d_in[9];
  const float* bv   = (const float*)d_in[10];
  const float* Wo   = (const float*)d_in[11];
  const float* bo   = (const float*)d_in[12];

  char* wsb = (char*)d_ws;
  int* flag = (int*)wsb;
  u16* qh = (u16*)(wsb + 256);
  u16* kh = (u16*)(wsb + 256 + 1*8388608);
  u16* vt = (u16*)(wsb + 256 + 2*8388608);
  u16* ao = (u16*)(wsb + 256 + 3*8388608);
  u16* wt = (u16*)(wsb + 256 + 4*8388608);
  unsigned* mbits = (unsigned*)(wsb + 256 + 5*8388608);
  u16* qc = (u16*)(wsb + 256 + 5*8388608 + 1048576);
  u16* kc = qc + (size_t)NB*QL*CH;
  u16* vc = kc + (size_t)NB*QL*CH;
  const size_t need_bits = 256 + 5ull*8388608 + 1048576;
  const size_t need_conv = need_bits + 3ull*NB*QL*CH*2;
  const bool usebits = (ws_size >= need_bits);
  const bool useconv = (ws_size >= need_conv);

  float* out  = (float*)d_out;
  float* attn = out + (size_t)NB*QL*CH;

  k_detect<<<1, 256, 0, stream>>>((const unsigned int*)mask, flag);
  if (usebits)
    k_maskpack<<<dim3(1024), 256, 0, stream>>>(mask, flag, mbits);
  if (useconv){
    k_prep<<<dim3(10240), 256, 0, stream>>>(Wq, Wk, Wv, Wo, wt, q, k, v, qc, kc, vc);
    k_gemm_qkv3<<<dim3(24,32), 512, 0, stream>>>(qc, kc, vc, wt, bq, bk, bv, qh, kh, vt);
  } else {
    k_prep<<<dim3(4096), 256, 0, stream>>>(Wq, Wk, Wv, Wo, wt, q, k, v, qc, kc, vc);
    k_gemm_qkv<<<dim3(16,64,3), 256, 0, stream>>>(q, k, v, wt, bq, bk, bv, qh, kh, vt);
  }
  if (usebits)
    k_attn32<<<dim3(64,16,2), 1024, 0, stream>>>(qh, kh, (const _Float16*)vt, bias, mbits, attn, ao);
  else
    k_attn<0><<<dim3(16,128,2), 1024, 0, stream>>>(qh, kh, (const _Float16*)vt, bias, mask, flag, mbits, attn, ao);
  if (useconv)
    k_gemm_out3<<<dim3(8,32), 512, 0, stream>>>(ao, wt + 3145728, bo, out);
  else
    k_gemm_out<<<dim3(16,64), 256, 0, stream>>>(ao, wt + 3145728, bo, out);
}

// Round 19
// 536.795 us; speedup vs baseline: 1.0105x; 1.0105x over previous
//
#include <hip/hip_runtime.h>
#include <hip/hip_bf16.h>

// MultiHeadAttention fused pipeline for MI355X (gfx950).
// Outputs: [0] out (2*2048*1024 f32), [1] attn (2*16*2048*2048 f32), concatenated in d_out.
// ws layout: [flag:256B][qh 8MB][kh 8MB][vt 8MB][ao 8MB][wt 8MB][mbits 1MB][qc 8][kc 8][vc 8] = ~66MB.

typedef __attribute__((ext_vector_type(8))) short bf16x8;
typedef __attribute__((ext_vector_type(8))) _Float16 f16x8;
typedef __attribute__((ext_vector_type(4))) float f32x4;
typedef __attribute__((ext_vector_type(4))) int i32x4;
typedef __attribute__((ext_vector_type(4))) _Float16 f16x4;
typedef unsigned short u16;

#define NB 2
#define QL 2048
#define KL 2048
#define CH 1024
#define NH 16
#define HD 64
#define SH_STRIDE 2600    // 16-row fallback attn stride
#define S32_STRIDE 2344   // 32-row attn stride: row 4688B (16B-aligned), 1172dw%32=20 (spread banks)

__device__ __forceinline__ u16 f2bf(float f){
  unsigned u = __float_as_uint(f);
  u += 0x7fffu + ((u >> 16) & 1u);   // RNE
  return (u16)(u >> 16);
}
__device__ __forceinline__ u16 f2h(float f){
  _Float16 h = (_Float16)f;
  return *(u16*)&h;
}

// ---------------- mask dtype detector: int32 0/1 vs packed bool bytes ----------------
__global__ void k_detect(const unsigned int* __restrict__ m, int* __restrict__ flag){
  unsigned v = m[threadIdx.x];
  unsigned long long b = __ballot(v > 1u);
  __shared__ int r[4];
  if ((threadIdx.x & 63) == 0) r[threadIdx.x >> 6] = (b != 0ULL);
  __syncthreads();
  if (threadIdx.x == 0) *flag = (r[0] | r[1] | r[2] | r[3]);
}

// ---------------- mask -> 1 bit/elem (1MB; L2/L3-resident) ----------------
__global__ __launch_bounds__(256) void k_maskpack(const void* __restrict__ maskp, const int* __restrict__ flag,
                                                  unsigned* __restrict__ mbits){
  const int idx = blockIdx.x*256 + threadIdx.x;
  unsigned out = 0;
  if (*flag){
    const unsigned* m8 = (const unsigned*)maskp + (size_t)idx*8;
    #pragma unroll
    for (int j=0;j<8;++j){
      unsigned wv = m8[j];
      out |= ((wv & 1u) | ((wv>>7)&2u) | ((wv>>14)&4u) | ((wv>>21)&8u)) << (4*j);
    }
  } else {
    const i32x4* m32 = (const i32x4*)maskp + (size_t)idx*8;
    #pragma unroll
    for (int j=0;j<8;++j){
      i32x4 v = m32[j];
      out |= (unsigned)((v[0]&1) | ((v[1]&1)<<1) | ((v[2]&1)<<2) | ((v[3]&1)<<3)) << (4*j);
    }
  }
  mbits[idx] = out;
}

// ---------------- merged prep: weight transpose (blocks 0..4095) + qkv f32->bf16 cvt (4096..10239) ----------------
__global__ __launch_bounds__(256) void k_prep(const float* __restrict__ Wq, const float* __restrict__ Wk,
                                              const float* __restrict__ Wv, const float* __restrict__ Wo,
                                              u16* __restrict__ wt,
                                              const float* __restrict__ q, const float* __restrict__ k,
                                              const float* __restrict__ v,
                                              u16* __restrict__ qc, u16* __restrict__ kc, u16* __restrict__ vc){
  const int bx = blockIdx.x;
  if (bx < 4096){
    const int z = bx >> 10, rem = bx & 1023;
    const int xt = rem & 31, yt = rem >> 5;
    const float* src = z==0 ? Wq : z==1 ? Wk : z==2 ? Wv : Wo;
    u16* dst = wt + (size_t)z * CH * CH;
    __shared__ float t[32][33];
    const int x = xt*32, y = yt*32;
    const int tx = threadIdx.x & 31, ty = threadIdx.x >> 5;
    #pragma unroll
    for (int j=0;j<32;j+=8) t[ty+j][tx] = src[(size_t)(y+ty+j)*CH + x + tx];
    __syncthreads();
    #pragma unroll
    for (int j=0;j<32;j+=8) dst[(size_t)(x+ty+j)*CH + y + tx] = f2bf(t[tx][ty+j]);
  } else {
    const int idx = bx - 4096;                  // 0..6143
    const int s = idx / 2048, blk = idx % 2048; // s: 0=q 1=k 2=v
    const float* in = s==0 ? q : s==1 ? k : v;
    u16* out = s==0 ? qc : s==1 ? kc : vc;
    const size_t i = ((size_t)blk*256 + threadIdx.x)*8;
    float4 lo = *(const float4*)&in[i];
    float4 hi = *(const float4*)&in[i+4];
    ushort4 a, b;
    a.x=f2bf(lo.x); a.y=f2bf(lo.y); a.z=f2bf(lo.z); a.w=f2bf(lo.w);
    b.x=f2bf(hi.x); b.y=f2bf(hi.y); b.z=f2bf(hi.z); b.w=f2bf(hi.w);
    *(ushort4*)&out[i] = a;
    *(ushort4*)&out[i+4] = b;
  }
}

// ---------------- 128x128 tile, 8-wave, BK=64, global_load_lds GEMM core (m97 structure) ----------------
__device__ __forceinline__ void gemm128_core(const u16* __restrict__ A, const u16* __restrict__ Bt,
                                             int m0, int n0, f32x4 acc[2][4]){
  __shared__ u16 As[128*64];
  __shared__ u16 Bs[128*64];
  const int tid = threadIdx.x, lane = tid & 63, w = tid >> 6;
  const int wm = w >> 1, wn = w & 1;
  const int lr = lane & 15, lg = lane >> 4;
  for (int k0 = 0; k0 < CH; k0 += 64){
    #pragma unroll
    for (int r=0;r<2;++r){
      const int chunk = r*512 + tid;
      const int row = chunk >> 3, ch = chunk & 7;
      __builtin_amdgcn_global_load_lds(
        (const __attribute__((address_space(1))) void*)&A[(size_t)(m0+row)*CH + k0 + ch*8],
        (__attribute__((address_space(3))) void*)&As[(r*512 + w*64)*8], 16, 0, 0);
      __builtin_amdgcn_global_load_lds(
        (const __attribute__((address_space(1))) void*)&Bt[(size_t)(n0+row)*CH + k0 + ch*8],
        (__attribute__((address_space(3))) void*)&Bs[(r*512 + w*64)*8], 16, 0, 0);
    }
    __syncthreads();
    #pragma unroll
    for (int kk=0; kk<2; ++kk){
      bf16x8 a0 = *(const bf16x8*)&As[(wm*32      + lr)*64 + (kk*4+lg)*8];
      bf16x8 a1 = *(const bf16x8*)&As[(wm*32 + 16 + lr)*64 + (kk*4+lg)*8];
      #pragma unroll
      for (int fj=0;fj<4;++fj){
        bf16x8 b = *(const bf16x8*)&Bs[(wn*64 + fj*16 + lr)*64 + (kk*4+lg)*8];
        acc[0][fj] = __builtin_amdgcn_mfma_f32_16x16x32_bf16(a0, b, acc[0][fj], 0,0,0);
        acc[1][fj] = __builtin_amdgcn_mfma_f32_16x16x32_bf16(a1, b, acc[1][fj], 0,0,0);
      }
    }
    __syncthreads();
  }
}

__global__ __launch_bounds__(512) void k_gemm_qkv3(const u16* __restrict__ qc, const u16* __restrict__ kc,
                                                   const u16* __restrict__ vc, const u16* __restrict__ wt,
                                                   const float* __restrict__ bq, const float* __restrict__ bk,
                                                   const float* __restrict__ bv,
                                                   u16* __restrict__ qh, u16* __restrict__ kh, u16* __restrict__ vt){
  const int z = blockIdx.x >> 3;
  const int n0 = (blockIdx.x & 7) * 128;
  const int m0 = blockIdx.y * 128;
  const u16* A  = z==0 ? qc : z==1 ? kc : vc;
  const u16* Bt = wt + (size_t)z*CH*CH;
  const float* bias = z==0 ? bq : z==1 ? bk : bv;
  const float scale = z==0 ? 0.03125f : 1.0f;
  u16* qk_dst = z==0 ? qh : kh;
  f32x4 acc[2][4] = {};
  gemm128_core(A, Bt, m0, n0, acc);
  const int lane = threadIdx.x & 63, w = threadIdx.x >> 6;
  const int wm = w >> 1, wn = w & 1;
  const int lr = lane & 15, lg = lane >> 4;
  #pragma unroll
  for (int fi=0;fi<2;++fi)
  #pragma unroll
  for (int fj=0;fj<4;++fj)
  #pragma unroll
  for (int r=0;r<4;++r){
    int row = m0 + wm*32 + fi*16 + lg*4 + r;
    int col = n0 + wn*64 + fj*16 + lr;
    float val = (acc[fi][fj][r] + bias[col]) * scale;
    int bb = row >> 11, ll = row & 2047, hh = col >> 6, dd = col & 63;
    if (z < 2) qk_dst[(((size_t)(bb*NH+hh)*QL + ll) << 6) + dd] = f2bf(val);
    else       vt[(((size_t)(bb*NH+hh) << 6) + dd)*KL + ll] = f2h(val);
  }
}

__global__ __launch_bounds__(512) void k_gemm_out3(const u16* __restrict__ ao, const u16* __restrict__ wto,
                                                   const float* __restrict__ bo, float* __restrict__ out){
  const int n0 = blockIdx.x * 128, m0 = blockIdx.y * 128;
  f32x4 acc[2][4] = {};
  gemm128_core(ao, wto, m0, n0, acc);
  const int lane = threadIdx.x & 63, w = threadIdx.x >> 6;
  const int wm = w >> 1, wn = w & 1;
  const int lr = lane & 15, lg = lane >> 4;
  #pragma unroll
  for (int fi=0;fi<2;++fi)
  #pragma unroll
  for (int fj=0;fj<4;++fj)
  #pragma unroll
  for (int r=0;r<4;++r){
    int row = m0 + wm*32 + fi*16 + lg*4 + r;
    int col = n0 + wn*64 + fj*16 + lr;
    out[(size_t)row*CH + col] = acc[fi][fj][r] + bo[col];
  }
}

// ---------------- legacy f32-input projection GEMMs (fallback when ws too small) ----------------
__global__ __launch_bounds__(256) void k_gemm_qkv(const float* __restrict__ q, const float* __restrict__ k,
                                                  const float* __restrict__ v, const u16* __restrict__ wt,
                                                  const float* __restrict__ bq, const float* __restrict__ bk,
                                                  const float* __restrict__ bv,
                                                  u16* __restrict__ qh, u16* __restrict__ kh, u16* __restrict__ vt){
  const int z = blockIdx.z;
  const float* A = z==0 ? q : z==1 ? k : v;
  const u16* Bt = wt + (size_t)z*CH*CH;
  const float* bias = z==0 ? bq : z==1 ? bk : bv;
  u16* Cp = z==0 ? qh : z==1 ? kh : vt;
  const float scale = (z==0) ? 0.03125f : 1.0f;
  __shared__ u16 As[64][72];
  __shared__ u16 Bs[64][72];
  const int m0 = blockIdx.y*64, n0 = blockIdx.x*64;
  const int tid = threadIdx.x, lane = tid & 63, w = tid >> 6;
  const int wm = w >> 1, wn = w & 1;
  const int lr = lane & 15, lg = lane >> 4;
  f32x4 acc[2][2] = {};
  for (int k0 = 0; k0 < CH; k0 += 64){
    #pragma unroll
    for (int j=0;j<4;++j){
      int idx = tid + 256*j, r = idx >> 4, c = (idx & 15)*4;
      float4 vv = *(const float4*)&A[(size_t)(m0+r)*CH + k0 + c];
      ushort4 s; s.x=f2bf(vv.x); s.y=f2bf(vv.y); s.z=f2bf(vv.z); s.w=f2bf(vv.w);
      *(ushort4*)&As[r][c] = s;
    }
    #pragma unroll
    for (int j=0;j<2;++j){
      int idx = tid + 256*j, r = idx >> 3, c = (idx & 7)*8;
      *(uint4*)&Bs[r][c] = *(const uint4*)&Bt[(size_t)(n0+r)*CH + k0 + c];
    }
    __syncthreads();
    #pragma unroll
    for (int kk=0; kk<2; ++kk){
      bf16x8 a0 = *(const bf16x8*)&As[wm*32      + lr][kk*32 + lg*8];
      bf16x8 a1 = *(const bf16x8*)&As[wm*32 + 16 + lr][kk*32 + lg*8];
      bf16x8 b0 = *(const bf16x8*)&Bs[wn*32      + lr][kk*32 + lg*8];
      bf16x8 b1 = *(const bf16x8*)&Bs[wn*32 + 16 + lr][kk*32 + lg*8];
      acc[0][0] = __builtin_amdgcn_mfma_f32_16x16x32_bf16(a0,b0,acc[0][0],0,0,0);
      acc[0][1] = __builtin_amdgcn_mfma_f32_16x16x32_bf16(a0,b1,acc[0][1],0,0,0);
      acc[1][0] = __builtin_amdgcn_mfma_f32_16x16x32_bf16(a1,b0,acc[1][0],0,0,0);
      acc[1][1] = __builtin_amdgcn_mfma_f32_16x16x32_bf16(a1,b1,acc[1][1],0,0,0);
    }
    __syncthreads();
  }
  #pragma unroll
  for (int fi=0;fi<2;++fi)
  #pragma unroll
  for (int fj=0;fj<2;++fj)
  #pragma unroll
  for (int r=0;r<4;++r){
    int row = m0 + wm*32 + fi*16 + lg*4 + r;
    int col = n0 + wn*32 + fj*16 + lr;
    float val = (acc[fi][fj][r] + bias[col]) * scale;
    int bb = row >> 11, ll = row & 2047, hh = col >> 6, dd = col & 63;
    if (z < 2) Cp[(((size_t)(bb*NH+hh)*QL + ll) << 6) + dd] = f2bf(val);
    else       Cp[(((size_t)(bb*NH+hh) << 6) + dd)*KL + ll] = f2h(val);
  }
}

__global__ __launch_bounds__(256) void k_gemm_out(const u16* __restrict__ Ap, const u16* __restrict__ Bt,
                                                  const float* __restrict__ bias, float* __restrict__ Cp){
  __shared__ u16 As[64][72];
  __shared__ u16 Bs[64][72];
  const int m0 = blockIdx.y*64, n0 = blockIdx.x*64;
  const int tid = threadIdx.x, lane = tid & 63, w = tid >> 6;
  const int wm = w >> 1, wn = w & 1;
  const int lr = lane & 15, lg = lane >> 4;
  f32x4 acc[2][2] = {};
  for (int k0 = 0; k0 < CH; k0 += 64){
    #pragma unroll
    for (int j=0;j<2;++j){
      int idx = tid + 256*j, r = idx >> 3, c = (idx & 7)*8;
      *(uint4*)&As[r][c] = *(const uint4*)&Ap[(size_t)(m0+r)*CH + k0 + c];
      *(uint4*)&Bs[r][c] = *(const uint4*)&Bt[(size_t)(n0+r)*CH + k0 + c];
    }
    __syncthreads();
    #pragma unroll
    for (int kk=0; kk<2; ++kk){
      bf16x8 a0 = *(const bf16x8*)&As[wm*32      + lr][kk*32 + lg*8];
      bf16x8 a1 = *(const bf16x8*)&As[wm*32 + 16 + lr][kk*32 + lg*8];
      bf16x8 b0 = *(const bf16x8*)&Bs[wn*32      + lr][kk*32 + lg*8];
      bf16x8 b1 = *(const bf16x8*)&Bs[wn*32 + 16 + lr][kk*32 + lg*8];
      acc[0][0] = __builtin_amdgcn_mfma_f32_16x16x32_bf16(a0,b0,acc[0][0],0,0,0);
      acc[0][1] = __builtin_amdgcn_mfma_f32_16x16x32_bf16(a0,b1,acc[0][1],0,0,0);
      acc[1][0] = __builtin_amdgcn_mfma_f32_16x16x32_bf16(a1,b0,acc[1][0],0,0,0);
      acc[1][1] = __builtin_amdgcn_mfma_f32_16x16x32_bf16(a1,b1,acc[1][1],0,0,0);
    }
    __syncthreads();
  }
  #pragma unroll
  for (int fi=0;fi<2;++fi)
  #pragma unroll
  for (int fj=0;fj<2;++fj)
  #pragma unroll
  for (int r=0;r<4;++r){
    int row = m0 + wm*32 + fi*16 + lg*4 + r;
    int col = n0 + wn*32 + fj*16 + lr;
    Cp[(size_t)row*CH + col] = acc[fi][fj][r] + bias[col];
  }
}

// ---------------- 32-row fused attention (R17 exact: best measured, clean writes) ----------------
__global__ __launch_bounds__(1024, 1) void k_attn32(const u16* __restrict__ qh, const u16* __restrict__ kh,
                                              const _Float16* __restrict__ vt, const float* __restrict__ bias,
                                              const unsigned* __restrict__ mbits,
                                              float* __restrict__ attn, u16* __restrict__ ao){
  __shared__ _Float16 Sh[32][S32_STRIDE];   // 150.0 KB
  __shared__ float wsum[16][32];            // 2 KB
  __shared__ float inv_l[32];
  const int qt = blockIdx.x, h = blockIdx.y, b = blockIdx.z;
  const int q0 = qt*32, bh = b*NH + h;
  const int tid = threadIdx.x, lane = tid & 63, w = tid >> 6;
  const int lr = lane & 15, lg = lane >> 4;
  const float* bb = bias + ((size_t)bh*QL + q0)*KL;
  const u16* khb = kh + (size_t)bh*KL*HD;
  const _Float16* vtb = vt + (size_t)bh*HD*KL;
  const int c0 = w*128;

  // ---- phase 1: two 16-row groups (per-group bias hoist; compiler schedules) ----
  #pragma unroll
  for (int g=0; g<2; ++g){
    const int qrow = q0 + g*16;
    const u16* qb = qh + ((size_t)bh*QL + qrow)*HD;
    const bf16x8 qf0 = *(const bf16x8*)&qb[lr*HD +      lg*8];
    const bf16x8 qf1 = *(const bf16x8*)&qb[lr*HD + 32 + lg*8];
    f32x4 bi[8];
    unsigned mwd[8];
    #pragma unroll
    for (int ct=0; ct<8; ++ct){
      const int cb = c0 + ct*16 + lg*4;
      bi[ct] = *(const f32x4*)&bb[(size_t)(g*16+lr)*KL + cb];
      mwd[ct] = mbits[((size_t)b*QL + qrow + lr)*(KL/32) + (cb>>5)];
    }
    float ps = 0.f;
    #pragma unroll
    for (int ct=0; ct<8; ++ct){
      const int cb = c0 + ct*16 + lg*4;
      f32x4 acc = bi[ct];
      const int kcol = c0 + ct*16 + lr;
      bf16x8 kf0 = *(const bf16x8*)&khb[(size_t)kcol*HD +      lg*8];
      bf16x8 kf1 = *(const bf16x8*)&khb[(size_t)kcol*HD + 32 + lg*8];
      acc = __builtin_amdgcn_mfma_f32_16x16x32_bf16(kf0, qf0, acc, 0,0,0);   // swapped: D = S^T frag
      acc = __builtin_amdgcn_mfma_f32_16x16x32_bf16(kf1, qf1, acc, 0,0,0);
      const unsigned msel = (mwd[ct] >> (cb & 31)) & 0xFu;
      f16x4 sv;
      #pragma unroll
      for (int r=0;r<4;++r){
        float e = ((msel >> r) & 1u) ? 0.f : __expf(acc[r]);   // bounded logits: no max-sub
        sv[r] = (_Float16)e;
        ps += e;
      }
      *(f16x4*)&Sh[g*16+lr][cb] = sv;
    }
    ps += __shfl_xor(ps, 16);
    ps += __shfl_xor(ps, 32);
    if (lane < 16) wsum[w][g*16+lr] = ps;
  }
  __syncthreads();
  if (tid < 32){
    float s = 0.f;
    #pragma unroll
    for (int ww=0; ww<16; ++ww) s += wsum[ww][tid];
    inv_l[tid] = 1.f / s;
  }
  __syncthreads();

  if (w < 8){
    // ---- PV: d-strip (w&3)*16, row-half (w>>2)*16, full K; direct ao write ----
    const int d0 = (w & 3)*16, rh = (w >> 2)*16;
    f32x4 oacc = {};
    #pragma unroll
    for (int kb=0; kb<8; ++kb){
      f16x8 vf[8], af[8];
      #pragma unroll
      for (int i=0;i<8;++i){
        vf[i] = *(const f16x8*)&vtb[(size_t)(d0+lr)*KL + kb*256 + i*32 + lg*8];
        af[i] = *(const f16x8*)&Sh[rh+lr][kb*256 + i*32 + lg*8];
      }
      #pragma unroll
      for (int i=0;i<8;++i)
        oacc = __builtin_amdgcn_mfma_f32_16x16x32_f16(af[i], vf[i], oacc, 0,0,0);
    }
    #pragma unroll
    for (int r=0;r<4;++r){
      const int row = rh + lg*4 + r;   // D: row=(lane>>4)*4+reg (q-row), col=lane&15 (d)
      ao[((size_t)b*QL + q0 + row)*CH + h*HD + d0 + lr] = f2bf(oacc[r] * inv_l[row]);
    }
  } else {
    // ---- writers: 4 rows each, normalized f32 attn, 1KB contiguous per instruction ----
    float* ob = attn + ((size_t)bh*QL + q0)*KL;
    const int r0 = (w - 8)*4;
    #pragma unroll
    for (int rr=0; rr<4; ++rr){
      const int row = r0 + rr;
      const float ivr = inv_l[row];
      float* orow = ob + (size_t)row*KL;
      #pragma unroll
      for (int ch=0; ch<8; ++ch){
        f16x4 hv = *(const f16x4*)&Sh[row][ch*256 + lane*4];
        f32x4 v;
        v[0]=(float)hv[0]*ivr; v[1]=(float)hv[1]*ivr; v[2]=(float)hv[2]*ivr; v[3]=(float)hv[3]*ivr;
        *(f32x4*)&orow[ch*256 + lane*4] = v;
      }
    }
  }
}

// ---------------- 16-row fused attention fallback (no mbits workspace) ----------------
template<int BITS>
__global__ __launch_bounds__(1024, 1) void k_attn(const u16* __restrict__ qh, const u16* __restrict__ kh,
                                              const _Float16* __restrict__ vt, const float* __restrict__ bias,
                                              const void* __restrict__ maskp, const int* __restrict__ flag,
                                              const unsigned* __restrict__ mbits,
                                              float* __restrict__ attn, u16* __restrict__ ao){
  __shared__ _Float16 Sh[16][SH_STRIDE];
  __shared__ float osum[8][16][17];
  __shared__ float wsum[16][16];
  __shared__ float inv_l[16];
  const int qt = BITS ? blockIdx.x : blockIdx.y;
  const int h  = BITS ? blockIdx.y : blockIdx.x;
  const int b  = blockIdx.z;
  const int q0 = qt*16, bh = b*NH + h;
  const int tid = threadIdx.x, lane = tid & 63, w = tid >> 6;
  const int lr = lane & 15, lg = lane >> 4;
  const u16* qb = qh + ((size_t)bh*QL + q0)*HD;
  const bf16x8 qf0 = *(const bf16x8*)&qb[lr*HD +      lg*8];
  const bf16x8 qf1 = *(const bf16x8*)&qb[lr*HD + 32 + lg*8];
  const float* bb = bias + ((size_t)bh*QL + q0)*KL;
  const u16* khb = kh + (size_t)bh*KL*HD;
  const _Float16* vtb = vt + (size_t)bh*HD*KL;
  const int c0 = w*128;

  f32x4 bi[8];
  unsigned mwd[8];
  #pragma unroll
  for (int ct=0; ct<8; ++ct){
    const int cb = c0 + ct*16 + lg*4;
    bi[ct] = *(const f32x4*)&bb[(size_t)lr*KL + cb];
    if (BITS) mwd[ct] = mbits[((size_t)b*QL + q0 + lr)*(KL/32) + (cb>>5)];
  }
  const int isbool = BITS ? 0 : *flag;
  const unsigned char* mb8 = (const unsigned char*)maskp + ((size_t)b*QL + q0)*KL;
  const int* mb32 = (const int*)maskp + ((size_t)b*QL + q0)*KL;

  float ps = 0.f;
  #pragma unroll
  for (int ct=0; ct<8; ++ct){
    const int cb = c0 + ct*16 + lg*4;
    f32x4 acc = bi[ct];
    const int kcol = c0 + ct*16 + lr;
    bf16x8 kf0 = *(const bf16x8*)&khb[(size_t)kcol*HD +      lg*8];
    bf16x8 kf1 = *(const bf16x8*)&khb[(size_t)kcol*HD + 32 + lg*8];
    acc = __builtin_amdgcn_mfma_f32_16x16x32_bf16(kf0, qf0, acc, 0,0,0);
    acc = __builtin_amdgcn_mfma_f32_16x16x32_bf16(kf1, qf1, acc, 0,0,0);
    unsigned msel;
    i32x4 mv;
    if (BITS){
      msel = (mwd[ct] >> (cb & 31)) & 0xFu;
    } else if (isbool){
      unsigned mw = *(const unsigned*)&mb8[(size_t)lr*KL + cb];
      msel = (mw&1u) | ((mw>>7)&2u) | ((mw>>14)&4u) | ((mw>>21)&8u);
    } else {
      mv = *(const i32x4*)&mb32[(size_t)lr*KL + cb];
      msel = (unsigned)((mv[0]&1) | ((mv[1]&1)<<1) | ((mv[2]&1)<<2) | ((mv[3]&1)<<3));
    }
    f16x4 sv;
    #pragma unroll
    for (int r=0;r<4;++r){
      float e = ((msel >> r) & 1u) ? 0.f : __expf(acc[r]);
      sv[r] = (_Float16)e;
      ps += e;
    }
    *(f16x4*)&Sh[lr][cb] = sv;
  }
  ps += __shfl_xor(ps, 16);
  ps += __shfl_xor(ps, 32);
  if (lane < 16) wsum[w][lr] = ps;
  __syncthreads();
  if (tid < 16){
    float s = 0.f;
    #pragma unroll
    for (int ww=0; ww<16; ++ww) s += wsum[ww][tid];
    inv_l[tid] = 1.f / s;
  }
  __syncthreads();

  if (w < 8){
    const int d0 = (w & 3)*16, kb0 = (w >> 2)*1024;
    f32x4 oacc = {};
    #pragma unroll
    for (int kb=0; kb<4; ++kb){
      f16x8 vf[8];
      #pragma unroll
      for (int i=0;i<8;++i)
        vf[i] = *(const f16x8*)&vtb[(size_t)(d0+lr)*KL + kb0 + kb*256 + i*32 + lg*8];
      #pragma unroll
      for (int i=0;i<8;++i){
        f16x8 a = *(const f16x8*)&Sh[lr][kb0 + kb*256 + i*32 + lg*8];
        oacc = __builtin_amdgcn_mfma_f32_16x16x32_f16(a, vf[i], oacc, 0,0,0);
      }
    }
    #pragma unroll
    for (int r=0;r<4;++r) osum[w][lg*4+r][lr] = oacc[r];
  } else {
    float* ob = attn + ((size_t)bh*QL + q0)*KL;
    const int r0 = (w - 8)*2;
    #pragma unroll
    for (int rr=0; rr<2; ++rr){
      const int row = r0 + rr;
      const float ivr = inv_l[row];
      #pragma unroll
      for (int ch=0; ch<8; ++ch){
        f16x4 hv = *(const f16x4*)&Sh[row][ch*256 + lane*4];
        f32x4 v;
        v[0]=(float)hv[0]*ivr; v[1]=(float)hv[1]*ivr; v[2]=(float)hv[2]*ivr; v[3]=(float)hv[3]*ivr;
        *(f32x4*)&ob[(size_t)row*KL + ch*256 + lane*4] = v;
      }
    }
  }
  __syncthreads();
  {
    const int row = tid >> 6, d = tid & 63;
    float o = (osum[d >> 4][row][d & 15] + osum[4 + (d >> 4)][row][d & 15]) * inv_l[row];
    ao[((size_t)b*QL + q0 + row)*CH + h*HD + d] = f2bf(o);
  }
}

extern "C" void kernel_launch(void* const* d_in, const int* in_sizes, int n_in,
                              void* d_out, int out_size, void* d_ws, size_t ws_size,
                              hipStream_t stream){
  const float* q    = (const float*)d_in[0];
  const float* k    = (const float*)d_in[1];
  const float* v    = (const float*)d_in[2];
  const void*  mask = d_in[3];
  const float* bias = (const float*)d_in[4];
  const float* Wq   = (const float*)d_in[5];
  const float* bq   = (const float*)d_in[6];
  const float* Wk   = (const float*)d_in[7];
  const float* bk   = (const float*)d_in[8];
  const float* Wv   = (const float*)d_in[9];
  const float* bv   = (const float*)d_in[10];
  const float* Wo   = (const float*)d_in[11];
  const float* bo   = (const float*)d_in[12];

  char* wsb = (char*)d_ws;
  int* flag = (int*)wsb;
  u16* qh = (u16*)(wsb + 256);
  u16* kh = (u16*)(wsb + 256 + 1*8388608);
  u16* vt = (u16*)(wsb + 256 + 2*8388608);
  u16* ao = (u16*)(wsb + 256 + 3*8388608);
  u16* wt = (u16*)(wsb + 256 + 4*8388608);
  unsigned* mbits = (unsigned*)(wsb + 256 + 5*8388608);
  u16* qc = (u16*)(wsb + 256 + 5*8388608 + 1048576);
  u16* kc = qc + (size_t)NB*QL*CH;
  u16* vc = kc + (size_t)NB*QL*CH;
  const size_t need_bits = 256 + 5ull*8388608 + 1048576;
  const size_t need_conv = need_bits + 3ull*NB*QL*CH*2;
  const bool usebits = (ws_size >= need_bits);
  const bool useconv = (ws_size >= need_conv);

  float* out  = (float*)d_out;
  float* attn = out + (size_t)NB*QL*CH;

  k_detect<<<1, 256, 0, stream>>>((const unsigned int*)mask, flag);
  if (usebits)
    k_maskpack<<<dim3(1024), 256, 0, stream>>>(mask, flag, mbits);
  if (useconv){
    k_prep<<<dim3(10240), 256, 0, stream>>>(Wq, Wk, Wv, Wo, wt, q, k, v, qc, kc, vc);
    k_gemm_qkv3<<<dim3(24,32), 512, 0, stream>>>(qc, kc, vc, wt, bq, bk, bv, qh, kh, vt);
  } else {
    k_prep<<<dim3(4096), 256, 0, stream>>>(Wq, Wk, Wv, Wo, wt, q, k, v, qc, kc, vc);
    k_gemm_qkv<<<dim3(16,64,3), 256, 0, stream>>>(q, k, v, wt, bq, bk, bv, qh, kh, vt);
  }
  if (usebits)
    k_attn32<<<dim3(64,16,2), 1024, 0, stream>>>(qh, kh, (const _Float16*)vt, bias, mbits, attn, ao);
  else
    k_attn<0><<<dim3(16,128,2), 1024, 0, stream>>>(qh, kh, (const _Float16*)vt, bias, mask, flag, mbits, attn, ao);
  if (useconv)
    k_gemm_out3<<<dim3(8,32), 512, 0, stream>>>(ao, wt + 3145728, bo, out);
  else
    k_gemm_out<<<dim3(16,64), 256, 0, stream>>>(ao, wt + 3145728, bo, out);
}

// Round 20
// 490.528 us; speedup vs baseline: 1.1058x; 1.0943x over previous
//
#include <hip/hip_runtime.h>
#include <hip/hip_bf16.h>

// MultiHeadAttention fused pipeline for MI355X (gfx950).
// Outputs: [0] out (2*2048*1024 f32), [1] attn (2*16*2048*2048 f32), concatenated in d_out.
// ws layout: [flag:256B][qh 8MB][kh 8MB][vt 8MB][ao 8MB][wt 8MB][mbits 1MB][qc 8][kc 8][vc 8] = ~66MB.

typedef __attribute__((ext_vector_type(8))) short bf16x8;
typedef __attribute__((ext_vector_type(8))) _Float16 f16x8;
typedef __attribute__((ext_vector_type(4))) float f32x4;
typedef __attribute__((ext_vector_type(4))) int i32x4;
typedef __attribute__((ext_vector_type(4))) _Float16 f16x4;
typedef unsigned short u16;

#define NB 2
#define QL 2048
#define KL 2048
#define CH 1024
#define NH 16
#define HD 64
#define SH_STRIDE 2600    // 16-row fallback attn stride
#define S32_STRIDE 2344   // 32-row attn stride: row 4688B (16B-aligned), 1172dw%32=20 (spread banks)

__device__ __forceinline__ u16 f2bf(float f){
  unsigned u = __float_as_uint(f);
  u += 0x7fffu + ((u >> 16) & 1u);   // RNE
  return (u16)(u >> 16);
}
__device__ __forceinline__ u16 f2h(float f){
  _Float16 h = (_Float16)f;
  return *(u16*)&h;
}

// ---------------- mask dtype detector: int32 0/1 vs packed bool bytes ----------------
__global__ void k_detect(const unsigned int* __restrict__ m, int* __restrict__ flag){
  unsigned v = m[threadIdx.x];
  unsigned long long b = __ballot(v > 1u);
  __shared__ int r[4];
  if ((threadIdx.x & 63) == 0) r[threadIdx.x >> 6] = (b != 0ULL);
  __syncthreads();
  if (threadIdx.x == 0) *flag = (r[0] | r[1] | r[2] | r[3]);
}

// ---------------- mask -> 1 bit/elem (1MB; L2/L3-resident) ----------------
__global__ __launch_bounds__(256) void k_maskpack(const void* __restrict__ maskp, const int* __restrict__ flag,
                                                  unsigned* __restrict__ mbits){
  const int idx = blockIdx.x*256 + threadIdx.x;
  unsigned out = 0;
  if (*flag){
    const unsigned* m8 = (const unsigned*)maskp + (size_t)idx*8;
    #pragma unroll
    for (int j=0;j<8;++j){
      unsigned wv = m8[j];
      out |= ((wv & 1u) | ((wv>>7)&2u) | ((wv>>14)&4u) | ((wv>>21)&8u)) << (4*j);
    }
  } else {
    const i32x4* m32 = (const i32x4*)maskp + (size_t)idx*8;
    #pragma unroll
    for (int j=0;j<8;++j){
      i32x4 v = m32[j];
      out |= (unsigned)((v[0]&1) | ((v[1]&1)<<1) | ((v[2]&1)<<2) | ((v[3]&1)<<3)) << (4*j);
    }
  }
  mbits[idx] = out;
}

// ---------------- merged prep: weight transpose (blocks 0..4095) + qkv f32->bf16 cvt (4096..10239) ----------------
__global__ __launch_bounds__(256) void k_prep(const float* __restrict__ Wq, const float* __restrict__ Wk,
                                              const float* __restrict__ Wv, const float* __restrict__ Wo,
                                              u16* __restrict__ wt,
                                              const float* __restrict__ q, const float* __restrict__ k,
                                              const float* __restrict__ v,
                                              u16* __restrict__ qc, u16* __restrict__ kc, u16* __restrict__ vc){
  const int bx = blockIdx.x;
  if (bx < 4096){
    const int z = bx >> 10, rem = bx & 1023;
    const int xt = rem & 31, yt = rem >> 5;
    const float* src = z==0 ? Wq : z==1 ? Wk : z==2 ? Wv : Wo;
    u16* dst = wt + (size_t)z * CH * CH;
    __shared__ float t[32][33];
    const int x = xt*32, y = yt*32;
    const int tx = threadIdx.x & 31, ty = threadIdx.x >> 5;
    #pragma unroll
    for (int j=0;j<32;j+=8) t[ty+j][tx] = src[(size_t)(y+ty+j)*CH + x + tx];
    __syncthreads();
    #pragma unroll
    for (int j=0;j<32;j+=8) dst[(size_t)(x+ty+j)*CH + y + tx] = f2bf(t[tx][ty+j]);
  } else {
    const int idx = bx - 4096;                  // 0..6143
    const int s = idx / 2048, blk = idx % 2048; // s: 0=q 1=k 2=v
    const float* in = s==0 ? q : s==1 ? k : v;
    u16* out = s==0 ? qc : s==1 ? kc : vc;
    const size_t i = ((size_t)blk*256 + threadIdx.x)*8;
    float4 lo = *(const float4*)&in[i];
    float4 hi = *(const float4*)&in[i+4];
    ushort4 a, b;
    a.x=f2bf(lo.x); a.y=f2bf(lo.y); a.z=f2bf(lo.z); a.w=f2bf(lo.w);
    b.x=f2bf(hi.x); b.y=f2bf(hi.y); b.z=f2bf(hi.z); b.w=f2bf(hi.w);
    *(ushort4*)&out[i] = a;
    *(ushort4*)&out[i+4] = b;
  }
}

// ---------------- 128x128 tile, 8-wave, BK=64, global_load_lds GEMM core (m97 structure) ----------------
__device__ __forceinline__ void gemm128_core(const u16* __restrict__ A, const u16* __restrict__ Bt,
                                             int m0, int n0, f32x4 acc[2][4]){
  __shared__ u16 As[128*64];
  __shared__ u16 Bs[128*64];
  const int tid = threadIdx.x, lane = tid & 63, w = tid >> 6;
  const int wm = w >> 1, wn = w & 1;
  const int lr = lane & 15, lg = lane >> 4;
  for (int k0 = 0; k0 < CH; k0 += 64){
    #pragma unroll
    for (int r=0;r<2;++r){
      const int chunk = r*512 + tid;
      const int row = chunk >> 3, ch = chunk & 7;
      __builtin_amdgcn_global_load_lds(
        (const __attribute__((address_space(1))) void*)&A[(size_t)(m0+row)*CH + k0 + ch*8],
        (__attribute__((address_space(3))) void*)&As[(r*512 + w*64)*8], 16, 0, 0);
      __builtin_amdgcn_global_load_lds(
        (const __attribute__((address_space(1))) void*)&Bt[(size_t)(n0+row)*CH + k0 + ch*8],
        (__attribute__((address_space(3))) void*)&Bs[(r*512 + w*64)*8], 16, 0, 0);
    }
    __syncthreads();
    #pragma unroll
    for (int kk=0; kk<2; ++kk){
      bf16x8 a0 = *(const bf16x8*)&As[(wm*32      + lr)*64 + (kk*4+lg)*8];
      bf16x8 a1 = *(const bf16x8*)&As[(wm*32 + 16 + lr)*64 + (kk*4+lg)*8];
      #pragma unroll
      for (int fj=0;fj<4;++fj){
        bf16x8 b = *(const bf16x8*)&Bs[(wn*64 + fj*16 + lr)*64 + (kk*4+lg)*8];
        acc[0][fj] = __builtin_amdgcn_mfma_f32_16x16x32_bf16(a0, b, acc[0][fj], 0,0,0);
        acc[1][fj] = __builtin_amdgcn_mfma_f32_16x16x32_bf16(a1, b, acc[1][fj], 0,0,0);
      }
    }
    __syncthreads();
  }
}

__global__ __launch_bounds__(512) void k_gemm_qkv3(const u16* __restrict__ qc, const u16* __restrict__ kc,
                                                   const u16* __restrict__ vc, const u16* __restrict__ wt,
                                                   const float* __restrict__ bq, const float* __restrict__ bk,
                                                   const float* __restrict__ bv,
                                                   u16* __restrict__ qh, u16* __restrict__ kh, u16* __restrict__ vt){
  const int z = blockIdx.x >> 3;
  const int n0 = (blockIdx.x & 7) * 128;
  const int m0 = blockIdx.y * 128;
  const u16* A  = z==0 ? qc : z==1 ? kc : vc;
  const u16* Bt = wt + (size_t)z*CH*CH;
  const float* bias = z==0 ? bq : z==1 ? bk : bv;
  const float scale = z==0 ? 0.03125f : 1.0f;
  u16* qk_dst = z==0 ? qh : kh;
  f32x4 acc[2][4] = {};
  gemm128_core(A, Bt, m0, n0, acc);
  const int lane = threadIdx.x & 63, w = threadIdx.x >> 6;
  const int wm = w >> 1, wn = w & 1;
  const int lr = lane & 15, lg = lane >> 4;
  #pragma unroll
  for (int fi=0;fi<2;++fi)
  #pragma unroll
  for (int fj=0;fj<4;++fj)
  #pragma unroll
  for (int r=0;r<4;++r){
    int row = m0 + wm*32 + fi*16 + lg*4 + r;
    int col = n0 + wn*64 + fj*16 + lr;
    float val = (acc[fi][fj][r] + bias[col]) * scale;
    int bb = row >> 11, ll = row & 2047, hh = col >> 6, dd = col & 63;
    if (z < 2) qk_dst[(((size_t)(bb*NH+hh)*QL + ll) << 6) + dd] = f2bf(val);
    else       vt[(((size_t)(bb*NH+hh) << 6) + dd)*KL + ll] = f2h(val);
  }
}

__global__ __launch_bounds__(512) void k_gemm_out3(const u16* __restrict__ ao, const u16* __restrict__ wto,
                                                   const float* __restrict__ bo, float* __restrict__ out){
  const int n0 = blockIdx.x * 128, m0 = blockIdx.y * 128;
  f32x4 acc[2][4] = {};
  gemm128_core(ao, wto, m0, n0, acc);
  const int lane = threadIdx.x & 63, w = threadIdx.x >> 6;
  const int wm = w >> 1, wn = w & 1;
  const int lr = lane & 15, lg = lane >> 4;
  #pragma unroll
  for (int fi=0;fi<2;++fi)
  #pragma unroll
  for (int fj=0;fj<4;++fj)
  #pragma unroll
  for (int r=0;r<4;++r){
    int row = m0 + wm*32 + fi*16 + lg*4 + r;
    int col = n0 + wn*64 + fj*16 + lr;
    out[(size_t)row*CH + col] = acc[fi][fj][r] + bo[col];
  }
}

// ---------------- legacy f32-input projection GEMMs (fallback when ws too small) ----------------
__global__ __launch_bounds__(256) void k_gemm_qkv(const float* __restrict__ q, const float* __restrict__ k,
                                                  const float* __restrict__ v, const u16* __restrict__ wt,
                                                  const float* __restrict__ bq, const float* __restrict__ bk,
                                                  const float* __restrict__ bv,
                                                  u16* __restrict__ qh, u16* __restrict__ kh, u16* __restrict__ vt){
  const int z = blockIdx.z;
  const float* A = z==0 ? q : z==1 ? k : v;
  const u16* Bt = wt + (size_t)z*CH*CH;
  const float* bias = z==0 ? bq : z==1 ? bk : bv;
  u16* Cp = z==0 ? qh : z==1 ? kh : vt;
  const float scale = (z==0) ? 0.03125f : 1.0f;
  __shared__ u16 As[64][72];
  __shared__ u16 Bs[64][72];
  const int m0 = blockIdx.y*64, n0 = blockIdx.x*64;
  const int tid = threadIdx.x, lane = tid & 63, w = tid >> 6;
  const int wm = w >> 1, wn = w & 1;
  const int lr = lane & 15, lg = lane >> 4;
  f32x4 acc[2][2] = {};
  for (int k0 = 0; k0 < CH; k0 += 64){
    #pragma unroll
    for (int j=0;j<4;++j){
      int idx = tid + 256*j, r = idx >> 4, c = (idx & 15)*4;
      float4 vv = *(const float4*)&A[(size_t)(m0+r)*CH + k0 + c];
      ushort4 s; s.x=f2bf(vv.x); s.y=f2bf(vv.y); s.z=f2bf(vv.z); s.w=f2bf(vv.w);
      *(ushort4*)&As[r][c] = s;
    }
    #pragma unroll
    for (int j=0;j<2;++j){
      int idx = tid + 256*j, r = idx >> 3, c = (idx & 7)*8;
      *(uint4*)&Bs[r][c] = *(const uint4*)&Bt[(size_t)(n0+r)*CH + k0 + c];
    }
    __syncthreads();
    #pragma unroll
    for (int kk=0; kk<2; ++kk){
      bf16x8 a0 = *(const bf16x8*)&As[wm*32      + lr][kk*32 + lg*8];
      bf16x8 a1 = *(const bf16x8*)&As[wm*32 + 16 + lr][kk*32 + lg*8];
      bf16x8 b0 = *(const bf16x8*)&Bs[wn*32      + lr][kk*32 + lg*8];
      bf16x8 b1 = *(const bf16x8*)&Bs[wn*32 + 16 + lr][kk*32 + lg*8];
      acc[0][0] = __builtin_amdgcn_mfma_f32_16x16x32_bf16(a0,b0,acc[0][0],0,0,0);
      acc[0][1] = __builtin_amdgcn_mfma_f32_16x16x32_bf16(a0,b1,acc[0][1],0,0,0);
      acc[1][0] = __builtin_amdgcn_mfma_f32_16x16x32_bf16(a1,b0,acc[1][0],0,0,0);
      acc[1][1] = __builtin_amdgcn_mfma_f32_16x16x32_bf16(a1,b1,acc[1][1],0,0,0);
    }
    __syncthreads();
  }
  #pragma unroll
  for (int fi=0;fi<2;++fi)
  #pragma unroll
  for (int fj=0;fj<2;++fj)
  #pragma unroll
  for (int r=0;r<4;++r){
    int row = m0 + wm*32 + fi*16 + lg*4 + r;
    int col = n0 + wn*32 + fj*16 + lr;
    float val = (acc[fi][fj][r] + bias[col]) * scale;
    int bb = row >> 11, ll = row & 2047, hh = col >> 6, dd = col & 63;
    if (z < 2) Cp[(((size_t)(bb*NH+hh)*QL + ll) << 6) + dd] = f2bf(val);
    else       Cp[(((size_t)(bb*NH+hh) << 6) + dd)*KL + ll] = f2h(val);
  }
}

__global__ __launch_bounds__(256) void k_gemm_out(const u16* __restrict__ Ap, const u16* __restrict__ Bt,
                                                  const float* __restrict__ bias, float* __restrict__ Cp){
  __shared__ u16 As[64][72];
  __shared__ u16 Bs[64][72];
  const int m0 = blockIdx.y*64, n0 = blockIdx.x*64;
  const int tid = threadIdx.x, lane = tid & 63, w = tid >> 6;
  const int wm = w >> 1, wn = w & 1;
  const int lr = lane & 15, lg = lane >> 4;
  f32x4 acc[2][2] = {};
  for (int k0 = 0; k0 < CH; k0 += 64){
    #pragma unroll
    for (int j=0;j<2;++j){
      int idx = tid + 256*j, r = idx >> 3, c = (idx & 7)*8;
      *(uint4*)&As[r][c] = *(const uint4*)&Ap[(size_t)(m0+r)*CH + k0 + c];
      *(uint4*)&Bs[r][c] = *(const uint4*)&Bt[(size_t)(n0+r)*CH + k0 + c];
    }
    __syncthreads();
    #pragma unroll
    for (int kk=0; kk<2; ++kk){
      bf16x8 a0 = *(const bf16x8*)&As[wm*32      + lr][kk*32 + lg*8];
      bf16x8 a1 = *(const bf16x8*)&As[wm*32 + 16 + lr][kk*32 + lg*8];
      bf16x8 b0 = *(const bf16x8*)&Bs[wn*32      + lr][kk*32 + lg*8];
      bf16x8 b1 = *(const bf16x8*)&Bs[wn*32 + 16 + lr][kk*32 + lg*8];
      acc[0][0] = __builtin_amdgcn_mfma_f32_16x16x32_bf16(a0,b0,acc[0][0],0,0,0);
      acc[0][1] = __builtin_amdgcn_mfma_f32_16x16x32_bf16(a0,b1,acc[0][1],0,0,0);
      acc[1][0] = __builtin_amdgcn_mfma_f32_16x16x32_bf16(a1,b0,acc[1][0],0,0,0);
      acc[1][1] = __builtin_amdgcn_mfma_f32_16x16x32_bf16(a1,b1,acc[1][1],0,0,0);
    }
    __syncthreads();
  }
  #pragma unroll
  for (int fi=0;fi<2;++fi)
  #pragma unroll
  for (int fj=0;fj<2;++fj)
  #pragma unroll
  for (int r=0;r<4;++r){
    int row = m0 + wm*32 + fi*16 + lg*4 + r;
    int col = n0 + wn*32 + fj*16 + lr;
    Cp[(size_t)row*CH + col] = acc[fi][fj][r] + bias[col];
  }
}

// ---------------- 32-row fused attention (R17 structure + register-resident K fragments) ----------------
// K frags depend only on (wave, ct, lane) — identical for both row-groups. Load ALL 16 once
// into kf[8][2] (64 VGPR): g0 gets a 3x-deeper read pipeline, g1 computes entirely from regs.
// VGPR headroom is free: LDS (150KB) caps occupancy at 1 block = 4 waves/SIMD, whose budget is 128.
__global__ __launch_bounds__(1024, 1) void k_attn32(const u16* __restrict__ qh, const u16* __restrict__ kh,
                                              const _Float16* __restrict__ vt, const float* __restrict__ bias,
                                              const unsigned* __restrict__ mbits,
                                              float* __restrict__ attn, u16* __restrict__ ao){
  __shared__ _Float16 Sh[32][S32_STRIDE];   // 150.0 KB
  __shared__ float wsum[16][32];            // 2 KB
  __shared__ float inv_l[32];
  const int qt = blockIdx.x, h = blockIdx.y, b = blockIdx.z;
  const int q0 = qt*32, bh = b*NH + h;
  const int tid = threadIdx.x, lane = tid & 63, w = tid >> 6;
  const int lr = lane & 15, lg = lane >> 4;
  const float* bb = bias + ((size_t)bh*QL + q0)*KL;
  const u16* khb = kh + (size_t)bh*KL*HD;
  const _Float16* vtb = vt + (size_t)bh*HD*KL;
  const int c0 = w*128;

  // ---- K fragments: load once, reuse for both groups (64 VGPR) ----
  bf16x8 kf[8][2];
  #pragma unroll
  for (int ct=0; ct<8; ++ct){
    const int kcol = c0 + ct*16 + lr;
    kf[ct][0] = *(const bf16x8*)&khb[(size_t)kcol*HD +      lg*8];
    kf[ct][1] = *(const bf16x8*)&khb[(size_t)kcol*HD + 32 + lg*8];
  }

  // ---- phase 1: two 16-row groups ----
  #pragma unroll
  for (int g=0; g<2; ++g){
    const int qrow = q0 + g*16;
    const u16* qb = qh + ((size_t)bh*QL + qrow)*HD;
    const bf16x8 qf0 = *(const bf16x8*)&qb[lr*HD +      lg*8];
    const bf16x8 qf1 = *(const bf16x8*)&qb[lr*HD + 32 + lg*8];
    f32x4 bi[8];
    unsigned mwd[8];
    #pragma unroll
    for (int ct=0; ct<8; ++ct){
      const int cb = c0 + ct*16 + lg*4;
      bi[ct] = *(const f32x4*)&bb[(size_t)(g*16+lr)*KL + cb];
      mwd[ct] = mbits[((size_t)b*QL + qrow + lr)*(KL/32) + (cb>>5)];
    }
    float ps = 0.f;
    #pragma unroll
    for (int ct=0; ct<8; ++ct){
      const int cb = c0 + ct*16 + lg*4;
      f32x4 acc = bi[ct];
      acc = __builtin_amdgcn_mfma_f32_16x16x32_bf16(kf[ct][0], qf0, acc, 0,0,0);   // swapped: D = S^T frag
      acc = __builtin_amdgcn_mfma_f32_16x16x32_bf16(kf[ct][1], qf1, acc, 0,0,0);
      const unsigned msel = (mwd[ct] >> (cb & 31)) & 0xFu;
      f16x4 sv;
      #pragma unroll
      for (int r=0;r<4;++r){
        float e = ((msel >> r) & 1u) ? 0.f : __expf(acc[r]);   // bounded logits: no max-sub
        sv[r] = (_Float16)e;
        ps += e;
      }
      *(f16x4*)&Sh[g*16+lr][cb] = sv;
    }
    ps += __shfl_xor(ps, 16);
    ps += __shfl_xor(ps, 32);
    if (lane < 16) wsum[w][g*16+lr] = ps;
  }
  __syncthreads();
  if (tid < 32){
    float s = 0.f;
    #pragma unroll
    for (int ww=0; ww<16; ++ww) s += wsum[ww][tid];
    inv_l[tid] = 1.f / s;
  }
  __syncthreads();

  if (w < 8){
    // ---- PV: d-strip (w&3)*16, row-half (w>>2)*16, full K; direct ao write ----
    const int d0 = (w & 3)*16, rh = (w >> 2)*16;
    f32x4 oacc = {};
    #pragma unroll
    for (int kb=0; kb<8; ++kb){
      f16x8 vf[8], af[8];
      #pragma unroll
      for (int i=0;i<8;++i){
        vf[i] = *(const f16x8*)&vtb[(size_t)(d0+lr)*KL + kb*256 + i*32 + lg*8];
        af[i] = *(const f16x8*)&Sh[rh+lr][kb*256 + i*32 + lg*8];
      }
      #pragma unroll
      for (int i=0;i<8;++i)
        oacc = __builtin_amdgcn_mfma_f32_16x16x32_f16(af[i], vf[i], oacc, 0,0,0);
    }
    #pragma unroll
    for (int r=0;r<4;++r){
      const int row = rh + lg*4 + r;   // D: row=(lane>>4)*4+reg (q-row), col=lane&15 (d)
      ao[((size_t)b*QL + q0 + row)*CH + h*HD + d0 + lr] = f2bf(oacc[r] * inv_l[row]);
    }
  } else {
    // ---- writers: 4 rows each, normalized f32 attn, 1KB contiguous per instruction ----
    float* ob = attn + ((size_t)bh*QL + q0)*KL;
    const int r0 = (w - 8)*4;
    #pragma unroll
    for (int rr=0; rr<4; ++rr){
      const int row = r0 + rr;
      const float ivr = inv_l[row];
      float* orow = ob + (size_t)row*KL;
      #pragma unroll
      for (int ch=0; ch<8; ++ch){
        f16x4 hv = *(const f16x4*)&Sh[row][ch*256 + lane*4];
        f32x4 v;
        v[0]=(float)hv[0]*ivr; v[1]=(float)hv[1]*ivr; v[2]=(float)hv[2]*ivr; v[3]=(float)hv[3]*ivr;
        *(f32x4*)&orow[ch*256 + lane*4] = v;
      }
    }
  }
}

// ---------------- 16-row fused attention fallback (no mbits workspace) ----------------
template<int BITS>
__global__ __launch_bounds__(1024, 1) void k_attn(const u16* __restrict__ qh, const u16* __restrict__ kh,
                                              const _Float16* __restrict__ vt, const float* __restrict__ bias,
                                              const void* __restrict__ maskp, const int* __restrict__ flag,
                                              const unsigned* __restrict__ mbits,
                                              float* __restrict__ attn, u16* __restrict__ ao){
  __shared__ _Float16 Sh[16][SH_STRIDE];
  __shared__ float osum[8][16][17];
  __shared__ float wsum[16][16];
  __shared__ float inv_l[16];
  const int qt = BITS ? blockIdx.x : blockIdx.y;
  const int h  = BITS ? blockIdx.y : blockIdx.x;
  const int b  = blockIdx.z;
  const int q0 = qt*16, bh = b*NH + h;
  const int tid = threadIdx.x, lane = tid & 63, w = tid >> 6;
  const int lr = lane & 15, lg = lane >> 4;
  const u16* qb = qh + ((size_t)bh*QL + q0)*HD;
  const bf16x8 qf0 = *(const bf16x8*)&qb[lr*HD +      lg*8];
  const bf16x8 qf1 = *(const bf16x8*)&qb[lr*HD + 32 + lg*8];
  const float* bb = bias + ((size_t)bh*QL + q0)*KL;
  const u16* khb = kh + (size_t)bh*KL*HD;
  const _Float16* vtb = vt + (size_t)bh*HD*KL;
  const int c0 = w*128;

  f32x4 bi[8];
  unsigned mwd[8];
  #pragma unroll
  for (int ct=0; ct<8; ++ct){
    const int cb = c0 + ct*16 + lg*4;
    bi[ct] = *(const f32x4*)&bb[(size_t)lr*KL + cb];
    if (BITS) mwd[ct] = mbits[((size_t)b*QL + q0 + lr)*(KL/32) + (cb>>5)];
  }
  const int isbool = BITS ? 0 : *flag;
  const unsigned char* mb8 = (const unsigned char*)maskp + ((size_t)b*QL + q0)*KL;
  const int* mb32 = (const int*)maskp + ((size_t)b*QL + q0)*KL;

  float ps = 0.f;
  #pragma unroll
  for (int ct=0; ct<8; ++ct){
    const int cb = c0 + ct*16 + lg*4;
    f32x4 acc = bi[ct];
    const int kcol = c0 + ct*16 + lr;
    bf16x8 kf0 = *(const bf16x8*)&khb[(size_t)kcol*HD +      lg*8];
    bf16x8 kf1 = *(const bf16x8*)&khb[(size_t)kcol*HD + 32 + lg*8];
    acc = __builtin_amdgcn_mfma_f32_16x16x32_bf16(kf0, qf0, acc, 0,0,0);
    acc = __builtin_amdgcn_mfma_f32_16x16x32_bf16(kf1, qf1, acc, 0,0,0);
    unsigned msel;
    i32x4 mv;
    if (BITS){
      msel = (mwd[ct] >> (cb & 31)) & 0xFu;
    } else if (isbool){
      unsigned mw = *(const unsigned*)&mb8[(size_t)lr*KL + cb];
      msel = (mw&1u) | ((mw>>7)&2u) | ((mw>>14)&4u) | ((mw>>21)&8u);
    } else {
      mv = *(const i32x4*)&mb32[(size_t)lr*KL + cb];
      msel = (unsigned)((mv[0]&1) | ((mv[1]&1)<<1) | ((mv[2]&1)<<2) | ((mv[3]&1)<<3));
    }
    f16x4 sv;
    #pragma unroll
    for (int r=0;r<4;++r){
      float e = ((msel >> r) & 1u) ? 0.f : __expf(acc[r]);
      sv[r] = (_Float16)e;
      ps += e;
    }
    *(f16x4*)&Sh[lr][cb] = sv;
  }
  ps += __shfl_xor(ps, 16);
  ps += __shfl_xor(ps, 32);
  if (lane < 16) wsum[w][lr] = ps;
  __syncthreads();
  if (tid < 16){
    float s = 0.f;
    #pragma unroll
    for (int ww=0; ww<16; ++ww) s += wsum[ww][tid];
    inv_l[tid] = 1.f / s;
  }
  __syncthreads();

  if (w < 8){
    const int d0 = (w & 3)*16, kb0 = (w >> 2)*1024;
    f32x4 oacc = {};
    #pragma unroll
    for (int kb=0; kb<4; ++kb){
      f16x8 vf[8];
      #pragma unroll
      for (int i=0;i<8;++i)
        vf[i] = *(const f16x8*)&vtb[(size_t)(d0+lr)*KL + kb0 + kb*256 + i*32 + lg*8];
      #pragma unroll
      for (int i=0;i<8;++i){
        f16x8 a = *(const f16x8*)&Sh[lr][kb0 + kb*256 + i*32 + lg*8];
        oacc = __builtin_amdgcn_mfma_f32_16x16x32_f16(a, vf[i], oacc, 0,0,0);
      }
    }
    #pragma unroll
    for (int r=0;r<4;++r) osum[w][lg*4+r][lr] = oacc[r];
  } else {
    float* ob = attn + ((size_t)bh*QL + q0)*KL;
    const int r0 = (w - 8)*2;
    #pragma unroll
    for (int rr=0; rr<2; ++rr){
      const int row = r0 + rr;
      const float ivr = inv_l[row];
      #pragma unroll
      for (int ch=0; ch<8; ++ch){
        f16x4 hv = *(const f16x4*)&Sh[row][ch*256 + lane*4];
        f32x4 v;
        v[0]=(float)hv[0]*ivr; v[1]=(float)hv[1]*ivr; v[2]=(float)hv[2]*ivr; v[3]=(float)hv[3]*ivr;
        *(f32x4*)&ob[(size_t)row*KL + ch*256 + lane*4] = v;
      }
    }
  }
  __syncthreads();
  {
    const int row = tid >> 6, d = tid & 63;
    float o = (osum[d >> 4][row][d & 15] + osum[4 + (d >> 4)][row][d & 15]) * inv_l[row];
    ao[((size_t)b*QL + q0 + row)*CH + h*HD + d] = f2bf(o);
  }
}

extern "C" void kernel_launch(void* const* d_in, const int* in_sizes, int n_in,
                              void* d_out, int out_size, void* d_ws, size_t ws_size,
                              hipStream_t stream){
  const float* q    = (const float*)d_in[0];
  const float* k    = (const float*)d_in[1];
  const float* v    = (const float*)d_in[2];
  const void*  mask = d_in[3];
  const float* bias = (const float*)d_in[4];
  const float* Wq   = (const float*)d_in[5];
  const float* bq   = (const float*)d_in[6];
  const float* Wk   = (const float*)d_in[7];
  const float* bk   = (const float*)d_in[8];
  const float* Wv   = (const float*)d_in[9];
  const float* bv   = (const float*)d_in[10];
  const float* Wo   = (const float*)d_in[11];
  const float* bo   = (const float*)d_in[12];

  char* wsb = (char*)d_ws;
  int* flag = (int*)wsb;
  u16* qh = (u16*)(wsb + 256);
  u16* kh = (u16*)(wsb + 256 + 1*8388608);
  u16* vt = (u16*)(wsb + 256 + 2*8388608);
  u16* ao = (u16*)(wsb + 256 + 3*8388608);
  u16* wt = (u16*)(wsb + 256 + 4*8388608);
  unsigned* mbits = (unsigned*)(wsb + 256 + 5*8388608);
  u16* qc = (u16*)(wsb + 256 + 5*8388608 + 1048576);
  u16* kc = qc + (size_t)NB*QL*CH;
  u16* vc = kc + (size_t)NB*QL*CH;
  const size_t need_bits = 256 + 5ull*8388608 + 1048576;
  const size_t need_conv = need_bits + 3ull*NB*QL*CH*2;
  const bool usebits = (ws_size >= need_bits);
  const bool useconv = (ws_size >= need_conv);

  float* out  = (float*)d_out;
  float* attn = out + (size_t)NB*QL*CH;

  k_detect<<<1, 256, 0, stream>>>((const unsigned int*)mask, flag);
  if (usebits)
    k_maskpack<<<dim3(1024), 256, 0, stream>>>(mask, flag, mbits);
  if (useconv){
    k_prep<<<dim3(10240), 256, 0, stream>>>(Wq, Wk, Wv, Wo, wt, q, k, v, qc, kc, vc);
    k_gemm_qkv3<<<dim3(24,32), 512, 0, stream>>>(qc, kc, vc, wt, bq, bk, bv, qh, kh, vt);
  } else {
    k_prep<<<dim3(4096), 256, 0, stream>>>(Wq, Wk, Wv, Wo, wt, q, k, v, qc, kc, vc);
    k_gemm_qkv<<<dim3(16,64,3), 256, 0, stream>>>(q, k, v, wt, bq, bk, bv, qh, kh, vt);
  }
  if (usebits)
    k_attn32<<<dim3(64,16,2), 1024, 0, stream>>>(qh, kh, (const _Float16*)vt, bias, mbits, attn, ao);
  else
    k_attn<0><<<dim3(16,128,2), 1024, 0, stream>>>(qh, kh, (const _Float16*)vt, bias, mask, flag, mbits, attn, ao);
  if (useconv)
    k_gemm_out3<<<dim3(8,32), 512, 0, stream>>>(ao, wt + 3145728, bo, out);
  else
    k_gemm_out<<<dim3(16,64), 256, 0, stream>>>(ao, wt + 3145728, bo, out);
}